// Round 13
// baseline (186.288 us; speedup 1.0000x reference)
//
#include <hip/hip_runtime.h>
#include <hip/hip_bf16.h>

#define IN_C   602
#define HID_C  256
#define OUT_C  41
#define N_TGT0 10240
#define N_TGT1 1024
#define E0     256000
#define E1     10240
#define KTOT   1216   // 608 (agg, padded) + 608 (x_tgt, padded)
#define NWK    (HID_C * KTOT)

typedef unsigned short u16;
typedef __attribute__((ext_vector_type(4))) float f32x4;
typedef __attribute__((ext_vector_type(8))) short bf16x8;

__device__ __forceinline__ u16 f2bf(float v) {
    union { float f; unsigned u; } c; c.f = v;
    unsigned u = c.u;
    u += 0x7fffu + ((u >> 16) & 1u);
    return (u16)(u >> 16);
}
__device__ __forceinline__ float bf2f(u16 v) {
    union { unsigned u; float f; } c; c.u = ((unsigned)v) << 16; return c.f;
}

__device__ __forceinline__ void gload16(const void* g, void* l) {
    __builtin_amdgcn_global_load_lds(
        (const __attribute__((address_space(1))) void*)g,
        (__attribute__((address_space(3))) void*)l, 16, 0, 0);
}

// ---------------- build: linked-list adjacency (both layers) + weight cast ----------------
__global__ __launch_bounds__(256) void build_kernel(
    const int* __restrict__ src0, const int* __restrict__ dst0,
    const int* __restrict__ src1, const int* __restrict__ dst1,
    int* __restrict__ head0, int* __restrict__ next0,
    int* __restrict__ head1, int* __restrict__ next1,
    const float* __restrict__ Wl, const float* __restrict__ Wr, u16* __restrict__ BT)
{
    int id = blockIdx.x * 256 + threadIdx.x;
    if (id < E0) {
        int p = atomicExch(&head0[dst0[id]], id);
        next0[id] = p;
    } else if (id < E0 + E1) {
        int e = id - E0;
        int p = atomicExch(&head1[dst1[e]], e);
        next1[e] = p;
    }
    if (id < NWK) {
        int n = id / KTOT, k = id - n * KTOT;
        float v = 0.f;
        if (k < IN_C)                        v = Wl[(size_t)k * HID_C + n];
        else if (k >= 608 && k < 608 + IN_C) v = Wr[(size_t)(k - 608) * HID_C + n];
        BT[id] = f2bf(v);
    }
}

// ---------------- layer-1 aggregation: sorted-sweep gather + x_tgt cast ----------------
// One wave per target. Pass 1: chain walk parks src indices in lane registers.
// Pass 2: bitonic-sort the 64-lane src register (d<=64; avg degree 25, d>64 is
// ~8-sigma). Pass 3: gather in ascending-src order, full MLP (5 float2 loads in
// flight + independent next shfl). All 2560 waves sweep x low->high in loose
// lockstep -> live window << L3 -> cross-wave duplicate rows (37%) hit L3.
__global__ __launch_bounds__(256) void agg0_sweep(
    const float* __restrict__ x, const int* __restrict__ head,
    const int* __restrict__ next, const int* __restrict__ srcv,
    u16* __restrict__ A)
{
    int t = blockIdx.x * 4 + (threadIdx.x >> 6);
    int lane = threadIdx.x & 63;

    float2 a0 = make_float2(0.f, 0.f), a1 = a0, a2 = a0, a3 = a0, a4 = a0;
    int d = 0;
    int my0 = 0x7fffffff, my1 = 0;   // my0 sentinel = INT_MAX (sorts to end)

    // ---- pass 1: chain walk -> lane registers (1-ahead prefetch)
    int cur = head[t];
    int s   = (cur >= 0) ? srcv[cur] : 0;
    int nxt = (cur >= 0) ? next[cur] : -1;
    while (cur >= 0) {
        int curN = nxt;
        int sN   = (curN >= 0) ? srcv[curN] : 0;
        int nxtN = (curN >= 0) ? next[curN] : -1;
        if (d < 64) {
            if (lane == d) my0 = s;
        } else if (d < 128) {
            if (lane == d - 64) my1 = s;
        } else {
            const float2* r = (const float2*)(x + (size_t)s * IN_C);
            float2 v0 = r[lane], v1 = r[lane + 64], v2 = r[lane + 128], v3 = r[lane + 192];
            a0.x += v0.x; a0.y += v0.y;
            a1.x += v1.x; a1.y += v1.y;
            a2.x += v2.x; a2.y += v2.y;
            a3.x += v3.x; a3.y += v3.y;
            if (lane < 45) {
                float2 v4 = r[lane + 256];
                a4.x += v4.x; a4.y += v4.y;
            }
        }
        ++d;
        cur = curN; s = sN; nxt = nxtN;
    }

    // ---- pass 2: bitonic sort of my0 across the wave (only when all fit: d<=64)
    if (d <= 64) {
        #pragma unroll
        for (int k = 2; k <= 64; k <<= 1) {
            #pragma unroll
            for (int j = k >> 1; j > 0; j >>= 1) {
                int o = __shfl_xor(my0, j);
                bool asc = (lane & k) == 0;
                bool low = (lane & j) == 0;
                my0 = (asc == low) ? min(my0, o) : max(my0, o);
            }
        }
    }

    // ---- pass 3: gather in sorted order (same issue structure as R10 = MLP-safe)
    int dcap = d < 128 ? d : 128;
    for (int j = 0; j < dcap; ++j) {
        int sj = __shfl((j < 64) ? my0 : my1, j & 63);
        const float2* r = (const float2*)(x + (size_t)sj * IN_C);
        float2 v0 = r[lane], v1 = r[lane + 64], v2 = r[lane + 128], v3 = r[lane + 192];
        a0.x += v0.x; a0.y += v0.y;
        a1.x += v1.x; a1.y += v1.y;
        a2.x += v2.x; a2.y += v2.y;
        a3.x += v3.x; a3.y += v3.y;
        if (lane < 45) {
            float2 v4 = r[lane + 256];
            a4.x += v4.x; a4.y += v4.y;
        }
    }

    float inv = 1.0f / (float)(d > 1 ? d : 1);
    ushort2* orow = (ushort2*)(A + (size_t)t * KTOT);
    ushort2 o;
    o.x = f2bf(a0.x * inv); o.y = f2bf(a0.y * inv); orow[lane]       = o;
    o.x = f2bf(a1.x * inv); o.y = f2bf(a1.y * inv); orow[lane + 64]  = o;
    o.x = f2bf(a2.x * inv); o.y = f2bf(a2.y * inv); orow[lane + 128] = o;
    o.x = f2bf(a3.x * inv); o.y = f2bf(a3.y * inv); orow[lane + 192] = o;
    if (lane < 45) {
        o.x = f2bf(a4.x * inv); o.y = f2bf(a4.y * inv); orow[lane + 256] = o;
    } else if (lane < 48) {   // pad cols 602..607
        o.x = 0; o.y = 0; orow[lane + 256] = o;
    }

    // x_tgt cast into cols 608..1215
    const float2* xt = (const float2*)(x + (size_t)t * IN_C);
    ushort2* orow2 = orow + 304;
    float2 w0 = xt[lane], w1 = xt[lane + 64], w2 = xt[lane + 128], w3 = xt[lane + 192];
    o.x = f2bf(w0.x); o.y = f2bf(w0.y); orow2[lane]       = o;
    o.x = f2bf(w1.x); o.y = f2bf(w1.y); orow2[lane + 64]  = o;
    o.x = f2bf(w2.x); o.y = f2bf(w2.y); orow2[lane + 128] = o;
    o.x = f2bf(w3.x); o.y = f2bf(w3.y); orow2[lane + 192] = o;
    if (lane < 45) {
        float2 w4 = xt[lane + 256];
        o.x = f2bf(w4.x); o.y = f2bf(w4.y); orow2[lane + 256] = o;
    } else if (lane < 48) {   // pad cols 1210..1215
        o.x = 0; o.y = 0; orow2[lane + 256] = o;
    }
}

// ---------------- layer-1 GEMM: 64x64 tile, 3-deep pipeline, counted vmcnt ----------------
#define GBM 64
#define GBN 64
#define GBK 64
#define GNIT (KTOT / GBK)   // 19

__global__ __launch_bounds__(256) void gemm1_tile(
    const u16* __restrict__ A, const u16* __restrict__ BT,
    const float* __restrict__ bias, u16* __restrict__ h)
{
    __shared__ __align__(16) u16 As[3][GBM * GBK];
    __shared__ __align__(16) u16 Bs[3][GBN * GBK];
    int tid = threadIdx.x;
    int w = tid >> 6, lane = tid & 63;
    int d = blockIdx.x;
    int ni = (d >> 3) & 3;
    int mi = (d & 7) + ((d >> 5) << 3);
    int bm = mi * GBM, bn = ni * GBN;

    int r16 = lane & 15;
    int g = lane >> 4;
    int wm2 = w >> 1, wn2 = w & 1;

    int srow = lane >> 3;
    int sslot = (lane & 7) ^ srow;
    const u16* gA0 = A  + (size_t)(bm + w * 16 + srow) * KTOT + sslot * 8;
    const u16* gA1 = gA0 + (size_t)8 * KTOT;
    const u16* gB0 = BT + (size_t)(bn + w * 16 + srow) * KTOT + sslot * 8;
    const u16* gB1 = gB0 + (size_t)8 * KTOT;

    int xr = r16 & 7;
    int rowA0 = wm2 * 32 + r16;
    int rowB0 = wn2 * 32 + r16;

    f32x4 acc[2][2] = {};

    auto stage = [&](int buf, int k0) {
        u16* dA = &As[buf][w * 1024];
        u16* dB = &Bs[buf][w * 1024];
        gload16(gA0 + k0, dA);
        gload16(gA1 + k0, dA + 512);
        gload16(gB0 + k0, dB);
        gload16(gB1 + k0, dB + 512);
    };

    stage(0, 0);
    stage(1, GBK);
    stage(2, 2 * GBK);
    asm volatile("s_waitcnt vmcnt(8)" ::: "memory");
    __builtin_amdgcn_sched_barrier(0);
    __builtin_amdgcn_s_barrier();

    int cur = 0;
    for (int it = 0; it < GNIT; ++it) {
        #pragma unroll
        for (int ks = 0; ks < 2; ++ks) {
            int sl = ((ks << 2) + g);
            bf16x8 a0 = *(const bf16x8*)(&As[cur][rowA0 * 64 + ((sl ^ xr) << 3)]);
            bf16x8 a1 = *(const bf16x8*)(&As[cur][(rowA0 + 16) * 64 + ((sl ^ xr) << 3)]);
            bf16x8 b0 = *(const bf16x8*)(&Bs[cur][rowB0 * 64 + ((sl ^ xr) << 3)]);
            bf16x8 b1 = *(const bf16x8*)(&Bs[cur][(rowB0 + 16) * 64 + ((sl ^ xr) << 3)]);
            acc[0][0] = __builtin_amdgcn_mfma_f32_16x16x32_bf16(a0, b0, acc[0][0], 0, 0, 0);
            acc[0][1] = __builtin_amdgcn_mfma_f32_16x16x32_bf16(a0, b1, acc[0][1], 0, 0, 0);
            acc[1][0] = __builtin_amdgcn_mfma_f32_16x16x32_bf16(a1, b0, acc[1][0], 0, 0, 0);
            acc[1][1] = __builtin_amdgcn_mfma_f32_16x16x32_bf16(a1, b1, acc[1][1], 0, 0, 0);
        }

        if (it + 1 < GNIT) {
            asm volatile("s_waitcnt lgkmcnt(0)" ::: "memory");
            __builtin_amdgcn_sched_barrier(0);
            __builtin_amdgcn_s_barrier();
            if (it + 3 < GNIT) {
                stage(cur, (it + 3) * GBK);
                asm volatile("s_waitcnt vmcnt(8)" ::: "memory");
            } else if (it + 2 < GNIT) {
                asm volatile("s_waitcnt vmcnt(4)" ::: "memory");
            } else {
                asm volatile("s_waitcnt vmcnt(0)" ::: "memory");
            }
            __builtin_amdgcn_sched_barrier(0);
            __builtin_amdgcn_s_barrier();
            cur = (cur == 2) ? 0 : cur + 1;
        }
    }

    int row4 = g * 4;
    #pragma unroll
    for (int fn = 0; fn < 2; ++fn) {
        int n = bn + wn2 * 32 + fn * 16 + r16;
        float b = bias[n];
        #pragma unroll
        for (int fm = 0; fm < 2; ++fm) {
            #pragma unroll
            for (int j = 0; j < 4; ++j) {
                int m = bm + wm2 * 32 + fm * 16 + row4 + j;
                float v = acc[fm][fn][j] + b;
                h[(size_t)m * HID_C + n] = f2bf(v > 0.f ? v : 0.f);
            }
        }
    }
}

// ---------------- layer-2: list pull + GEMM2 + log_softmax, fully fused ----------------
__global__ __launch_bounds__(64) void out_fused(
    const u16* __restrict__ h, const int* __restrict__ head,
    const int* __restrict__ next, const int* __restrict__ srcv,
    const float* __restrict__ Wl, const float* __restrict__ Wr,
    const float* __restrict__ bias, float* __restrict__ out)
{
    __shared__ float arow[HID_C];
    __shared__ float hrow[HID_C];
    int t = blockIdx.x;
    int lane = threadIdx.x;

    float4 acc = make_float4(0.f, 0.f, 0.f, 0.f);
    int d = 0;
    int cur = head[t];
    int s   = (cur >= 0) ? srcv[cur] : 0;
    int nxt = (cur >= 0) ? next[cur] : -1;
    while (cur >= 0) {
        ushort4 v = ((const ushort4*)(h + (size_t)s * HID_C))[lane];
        int curN = nxt;
        int sN   = (curN >= 0) ? srcv[curN] : 0;
        int nxtN = (curN >= 0) ? next[curN] : -1;
        acc.x += bf2f(v.x); acc.y += bf2f(v.y);
        acc.z += bf2f(v.z); acc.w += bf2f(v.w);
        ++d;
        cur = curN; s = sN; nxt = nxtN;
    }
    float inv = 1.0f / (float)(d > 1 ? d : 1);
    ((float4*)arow)[lane] = make_float4(acc.x * inv, acc.y * inv, acc.z * inv, acc.w * inv);
    ushort4 hv = ((const ushort4*)(h + (size_t)t * HID_C))[lane];
    ((float4*)hrow)[lane] = make_float4(bf2f(hv.x), bf2f(hv.y), bf2f(hv.z), bf2f(hv.w));
    __syncthreads();

    float v = 0.f;
    if (lane < OUT_C) {
        v = bias[lane];
        for (int k = 0; k < HID_C; ++k)
            v += arow[k] * Wl[k * OUT_C + lane] + hrow[k] * Wr[k * OUT_C + lane];
    }
    float m = (lane < OUT_C) ? v : -1e30f;
    #pragma unroll
    for (int off = 32; off; off >>= 1) m = fmaxf(m, __shfl_xor(m, off));
    float ex = (lane < OUT_C) ? expf(v - m) : 0.f;
    float sum = ex;
    #pragma unroll
    for (int off = 32; off; off >>= 1) sum += __shfl_xor(sum, off);
    float lse = m + logf(sum);
    if (lane < OUT_C) out[(size_t)t * OUT_C + lane] = v - lse;
}

// ---------------- launch ----------------

extern "C" void kernel_launch(void* const* d_in, const int* in_sizes, int n_in,
                              void* d_out, int out_size, void* d_ws, size_t ws_size,
                              hipStream_t stream) {
    const float* x    = (const float*)d_in[0];
    const int*   src0 = (const int*)d_in[1];
    const int*   dst0 = (const int*)d_in[2];
    const int*   src1 = (const int*)d_in[3];
    const int*   dst1 = (const int*)d_in[4];
    const float* Wl1  = (const float*)d_in[5];
    const float* Wr1  = (const float*)d_in[6];
    const float* b1   = (const float*)d_in[7];
    const float* Wl2  = (const float*)d_in[8];
    const float* Wr2  = (const float*)d_in[9];
    const float* b2   = (const float*)d_in[10];
    float* out = (float*)d_out;

    char* ws = (char*)d_ws;
    size_t off = 0;
    auto take = [&](size_t bytes) { void* p = ws + off; off += (bytes + 255) & ~(size_t)255; return p; };
    u16* A     = (u16*)take((size_t)N_TGT0 * KTOT * 2);
    u16* BT    = (u16*)take((size_t)HID_C * KTOT * 2);
    u16* h     = (u16*)take((size_t)N_TGT0 * HID_C * 2);
    int* head0 = (int*)take((size_t)(N_TGT0 + N_TGT1) * 4);
    int* head1 = head0 + N_TGT0;
    int* next0 = (int*)take((size_t)E0 * 4);
    int* next1 = (int*)take((size_t)E1 * 4);

    hipMemsetAsync(head0, 0xFF, (size_t)(N_TGT0 + N_TGT1) * sizeof(int), stream);

    build_kernel<<<(NWK + 255) / 256, 256, 0, stream>>>(
        src0, dst0, src1, dst1, head0, next0, head1, next1, Wl1, Wr1, BT);

    agg0_sweep<<<N_TGT0 / 4, 256, 0, stream>>>(x, head0, next0, src0, A);

    gemm1_tile<<<640, 256, 0, stream>>>(A, BT, b1, h);

    out_fused<<<N_TGT1, 64, 0, stream>>>(h, head1, next1, src1, Wl2, Wr2, b2, out);
}

// Round 14
// 179.918 us; speedup vs baseline: 1.0354x; 1.0354x over previous
//
#include <hip/hip_runtime.h>
#include <hip/hip_bf16.h>

#define IN_C   602
#define HID_C  256
#define OUT_C  41
#define N_TGT0 10240
#define N_TGT1 1024
#define E0     256000
#define E1     10240
#define KTOT   1216   // 608 (agg, padded) + 608 (x_tgt, padded)
#define NWK    (HID_C * KTOT)

typedef unsigned short u16;
typedef __attribute__((ext_vector_type(4))) float f32x4;
typedef __attribute__((ext_vector_type(8))) short bf16x8;

__device__ __forceinline__ u16 f2bf(float v) {
    union { float f; unsigned u; } c; c.f = v;
    unsigned u = c.u;
    u += 0x7fffu + ((u >> 16) & 1u);
    return (u16)(u >> 16);
}
__device__ __forceinline__ float bf2f(u16 v) {
    union { unsigned u; float f; } c; c.u = ((unsigned)v) << 16; return c.f;
}

__device__ __forceinline__ void gload16(const void* g, void* l) {
    __builtin_amdgcn_global_load_lds(
        (const __attribute__((address_space(1))) void*)g,
        (__attribute__((address_space(3))) void*)l, 16, 0, 0);
}

// ---------------- build: linked-list adjacency (both layers) + weight cast ----------------
__global__ __launch_bounds__(256) void build_kernel(
    const int* __restrict__ src0, const int* __restrict__ dst0,
    const int* __restrict__ src1, const int* __restrict__ dst1,
    int* __restrict__ head0, int* __restrict__ next0,
    int* __restrict__ head1, int* __restrict__ next1,
    const float* __restrict__ Wl, const float* __restrict__ Wr, u16* __restrict__ BT)
{
    int id = blockIdx.x * 256 + threadIdx.x;
    if (id < E0) {
        int p = atomicExch(&head0[dst0[id]], id);
        next0[id] = p;
    } else if (id < E0 + E1) {
        int e = id - E0;
        int p = atomicExch(&head1[dst1[e]], e);
        next1[e] = p;
    }
    if (id < NWK) {
        int n = id / KTOT, k = id - n * KTOT;
        float v = 0.f;
        if (k < IN_C)                        v = Wl[(size_t)k * HID_C + n];
        else if (k >= 608 && k < 608 + IN_C) v = Wr[(size_t)(k - 608) * HID_C + n];
        BT[id] = f2bf(v);
    }
}

// ---------------- layer-1 aggregation (linked-list walk) + x_tgt cast ----------------
// Best-measured version (R9, 180.3us total): one wave per target, INTERLEAVED
// chain-chase + row gather (chain latency hides under row loads). Verdicts from
// R10-R13: more MLP (4-edge unroll), 16B loads, phased dedupe, and sorted-sweep
// dedupe are all neutral-to-worse — the gather is memory-system-bound at
// ~4.7 TB/s effective for random 2.4KB rows.
__global__ __launch_bounds__(256) void agg0_ll(
    const float* __restrict__ x, const int* __restrict__ head,
    const int* __restrict__ next, const int* __restrict__ srcv,
    u16* __restrict__ A)
{
    int t = blockIdx.x * 4 + (threadIdx.x >> 6);
    int lane = threadIdx.x & 63;

    float2 a0 = make_float2(0.f, 0.f), a1 = a0, a2 = a0, a3 = a0, a4 = a0;
    int d = 0;

    int cur = head[t];
    int s   = (cur >= 0) ? srcv[cur] : 0;
    int nxt = (cur >= 0) ? next[cur] : -1;
    while (cur >= 0) {
        const float2* r = (const float2*)(x + (size_t)s * IN_C);
        float2 v0 = r[lane], v1 = r[lane + 64], v2 = r[lane + 128], v3 = r[lane + 192];
        int curN = nxt;
        int sN   = (curN >= 0) ? srcv[curN] : 0;
        int nxtN = (curN >= 0) ? next[curN] : -1;
        a0.x += v0.x; a0.y += v0.y;
        a1.x += v1.x; a1.y += v1.y;
        a2.x += v2.x; a2.y += v2.y;
        a3.x += v3.x; a3.y += v3.y;
        if (lane < 45) {
            float2 v4 = r[lane + 256];
            a4.x += v4.x; a4.y += v4.y;
        }
        ++d;
        cur = curN; s = sN; nxt = nxtN;
    }

    float inv = 1.0f / (float)(d > 1 ? d : 1);
    ushort2* orow = (ushort2*)(A + (size_t)t * KTOT);
    ushort2 o;
    o.x = f2bf(a0.x * inv); o.y = f2bf(a0.y * inv); orow[lane]       = o;
    o.x = f2bf(a1.x * inv); o.y = f2bf(a1.y * inv); orow[lane + 64]  = o;
    o.x = f2bf(a2.x * inv); o.y = f2bf(a2.y * inv); orow[lane + 128] = o;
    o.x = f2bf(a3.x * inv); o.y = f2bf(a3.y * inv); orow[lane + 192] = o;
    if (lane < 45) {
        o.x = f2bf(a4.x * inv); o.y = f2bf(a4.y * inv); orow[lane + 256] = o;
    } else if (lane < 48) {   // pad cols 602..607
        o.x = 0; o.y = 0; orow[lane + 256] = o;
    }

    const float2* xt = (const float2*)(x + (size_t)t * IN_C);
    ushort2* orow2 = orow + 304;
    float2 w0 = xt[lane], w1 = xt[lane + 64], w2 = xt[lane + 128], w3 = xt[lane + 192];
    o.x = f2bf(w0.x); o.y = f2bf(w0.y); orow2[lane]       = o;
    o.x = f2bf(w1.x); o.y = f2bf(w1.y); orow2[lane + 64]  = o;
    o.x = f2bf(w2.x); o.y = f2bf(w2.y); orow2[lane + 128] = o;
    o.x = f2bf(w3.x); o.y = f2bf(w3.y); orow2[lane + 192] = o;
    if (lane < 45) {
        float2 w4 = xt[lane + 256];
        o.x = f2bf(w4.x); o.y = f2bf(w4.y); orow2[lane + 256] = o;
    } else if (lane < 48) {   // pad cols 1210..1215
        o.x = 0; o.y = 0; orow2[lane + 256] = o;
    }
}

// ---------------- layer-1 GEMM: 64x64 tile, 3-deep pipeline, counted vmcnt ----------------
// At its structural floor (~14us): R12 showed depth-3 == depth-2; remaining
// cost is barrier/issue, not load latency.
#define GBM 64
#define GBN 64
#define GBK 64
#define GNIT (KTOT / GBK)   // 19

__global__ __launch_bounds__(256) void gemm1_tile(
    const u16* __restrict__ A, const u16* __restrict__ BT,
    const float* __restrict__ bias, u16* __restrict__ h)
{
    __shared__ __align__(16) u16 As[3][GBM * GBK];
    __shared__ __align__(16) u16 Bs[3][GBN * GBK];
    int tid = threadIdx.x;
    int w = tid >> 6, lane = tid & 63;
    int d = blockIdx.x;
    int ni = (d >> 3) & 3;
    int mi = (d & 7) + ((d >> 5) << 3);
    int bm = mi * GBM, bn = ni * GBN;

    int r16 = lane & 15;
    int g = lane >> 4;
    int wm2 = w >> 1, wn2 = w & 1;

    int srow = lane >> 3;
    int sslot = (lane & 7) ^ srow;
    const u16* gA0 = A  + (size_t)(bm + w * 16 + srow) * KTOT + sslot * 8;
    const u16* gA1 = gA0 + (size_t)8 * KTOT;
    const u16* gB0 = BT + (size_t)(bn + w * 16 + srow) * KTOT + sslot * 8;
    const u16* gB1 = gB0 + (size_t)8 * KTOT;

    int xr = r16 & 7;
    int rowA0 = wm2 * 32 + r16;
    int rowB0 = wn2 * 32 + r16;

    f32x4 acc[2][2] = {};

    auto stage = [&](int buf, int k0) {
        u16* dA = &As[buf][w * 1024];
        u16* dB = &Bs[buf][w * 1024];
        gload16(gA0 + k0, dA);
        gload16(gA1 + k0, dA + 512);
        gload16(gB0 + k0, dB);
        gload16(gB1 + k0, dB + 512);
    };

    stage(0, 0);
    stage(1, GBK);
    stage(2, 2 * GBK);
    asm volatile("s_waitcnt vmcnt(8)" ::: "memory");
    __builtin_amdgcn_sched_barrier(0);
    __builtin_amdgcn_s_barrier();

    int cur = 0;
    for (int it = 0; it < GNIT; ++it) {
        #pragma unroll
        for (int ks = 0; ks < 2; ++ks) {
            int sl = ((ks << 2) + g);
            bf16x8 a0 = *(const bf16x8*)(&As[cur][rowA0 * 64 + ((sl ^ xr) << 3)]);
            bf16x8 a1 = *(const bf16x8*)(&As[cur][(rowA0 + 16) * 64 + ((sl ^ xr) << 3)]);
            bf16x8 b0 = *(const bf16x8*)(&Bs[cur][rowB0 * 64 + ((sl ^ xr) << 3)]);
            bf16x8 b1 = *(const bf16x8*)(&Bs[cur][(rowB0 + 16) * 64 + ((sl ^ xr) << 3)]);
            acc[0][0] = __builtin_amdgcn_mfma_f32_16x16x32_bf16(a0, b0, acc[0][0], 0, 0, 0);
            acc[0][1] = __builtin_amdgcn_mfma_f32_16x16x32_bf16(a0, b1, acc[0][1], 0, 0, 0);
            acc[1][0] = __builtin_amdgcn_mfma_f32_16x16x32_bf16(a1, b0, acc[1][0], 0, 0, 0);
            acc[1][1] = __builtin_amdgcn_mfma_f32_16x16x32_bf16(a1, b1, acc[1][1], 0, 0, 0);
        }

        if (it + 1 < GNIT) {
            asm volatile("s_waitcnt lgkmcnt(0)" ::: "memory");
            __builtin_amdgcn_sched_barrier(0);
            __builtin_amdgcn_s_barrier();
            if (it + 3 < GNIT) {
                stage(cur, (it + 3) * GBK);
                asm volatile("s_waitcnt vmcnt(8)" ::: "memory");
            } else if (it + 2 < GNIT) {
                asm volatile("s_waitcnt vmcnt(4)" ::: "memory");
            } else {
                asm volatile("s_waitcnt vmcnt(0)" ::: "memory");
            }
            __builtin_amdgcn_sched_barrier(0);
            __builtin_amdgcn_s_barrier();
            cur = (cur == 2) ? 0 : cur + 1;
        }
    }

    int row4 = g * 4;
    #pragma unroll
    for (int fn = 0; fn < 2; ++fn) {
        int n = bn + wn2 * 32 + fn * 16 + r16;
        float b = bias[n];
        #pragma unroll
        for (int fm = 0; fm < 2; ++fm) {
            #pragma unroll
            for (int j = 0; j < 4; ++j) {
                int m = bm + wm2 * 32 + fm * 16 + row4 + j;
                float v = acc[fm][fn][j] + b;
                h[(size_t)m * HID_C + n] = f2bf(v > 0.f ? v : 0.f);
            }
        }
    }
}

// ---------------- layer-2: list pull + GEMM2 + log_softmax, fully fused ----------------
__global__ __launch_bounds__(64) void out_fused(
    const u16* __restrict__ h, const int* __restrict__ head,
    const int* __restrict__ next, const int* __restrict__ srcv,
    const float* __restrict__ Wl, const float* __restrict__ Wr,
    const float* __restrict__ bias, float* __restrict__ out)
{
    __shared__ float arow[HID_C];
    __shared__ float hrow[HID_C];
    int t = blockIdx.x;
    int lane = threadIdx.x;

    float4 acc = make_float4(0.f, 0.f, 0.f, 0.f);
    int d = 0;
    int cur = head[t];
    int s   = (cur >= 0) ? srcv[cur] : 0;
    int nxt = (cur >= 0) ? next[cur] : -1;
    while (cur >= 0) {
        ushort4 v = ((const ushort4*)(h + (size_t)s * HID_C))[lane];
        int curN = nxt;
        int sN   = (curN >= 0) ? srcv[curN] : 0;
        int nxtN = (curN >= 0) ? next[curN] : -1;
        acc.x += bf2f(v.x); acc.y += bf2f(v.y);
        acc.z += bf2f(v.z); acc.w += bf2f(v.w);
        ++d;
        cur = curN; s = sN; nxt = nxtN;
    }
    float inv = 1.0f / (float)(d > 1 ? d : 1);
    ((float4*)arow)[lane] = make_float4(acc.x * inv, acc.y * inv, acc.z * inv, acc.w * inv);
    ushort4 hv = ((const ushort4*)(h + (size_t)t * HID_C))[lane];
    ((float4*)hrow)[lane] = make_float4(bf2f(hv.x), bf2f(hv.y), bf2f(hv.z), bf2f(hv.w));
    __syncthreads();

    float v = 0.f;
    if (lane < OUT_C) {
        v = bias[lane];
        for (int k = 0; k < HID_C; ++k)
            v += arow[k] * Wl[k * OUT_C + lane] + hrow[k] * Wr[k * OUT_C + lane];
    }
    float m = (lane < OUT_C) ? v : -1e30f;
    #pragma unroll
    for (int off = 32; off; off >>= 1) m = fmaxf(m, __shfl_xor(m, off));
    float ex = (lane < OUT_C) ? expf(v - m) : 0.f;
    float sum = ex;
    #pragma unroll
    for (int off = 32; off; off >>= 1) sum += __shfl_xor(sum, off);
    float lse = m + logf(sum);
    if (lane < OUT_C) out[(size_t)t * OUT_C + lane] = v - lse;
}

// ---------------- launch ----------------

extern "C" void kernel_launch(void* const* d_in, const int* in_sizes, int n_in,
                              void* d_out, int out_size, void* d_ws, size_t ws_size,
                              hipStream_t stream) {
    const float* x    = (const float*)d_in[0];
    const int*   src0 = (const int*)d_in[1];
    const int*   dst0 = (const int*)d_in[2];
    const int*   src1 = (const int*)d_in[3];
    const int*   dst1 = (const int*)d_in[4];
    const float* Wl1  = (const float*)d_in[5];
    const float* Wr1  = (const float*)d_in[6];
    const float* b1   = (const float*)d_in[7];
    const float* Wl2  = (const float*)d_in[8];
    const float* Wr2  = (const float*)d_in[9];
    const float* b2   = (const float*)d_in[10];
    float* out = (float*)d_out;

    char* ws = (char*)d_ws;
    size_t off = 0;
    auto take = [&](size_t bytes) { void* p = ws + off; off += (bytes + 255) & ~(size_t)255; return p; };
    u16* A     = (u16*)take((size_t)N_TGT0 * KTOT * 2);
    u16* BT    = (u16*)take((size_t)HID_C * KTOT * 2);
    u16* h     = (u16*)take((size_t)N_TGT0 * HID_C * 2);
    int* head0 = (int*)take((size_t)(N_TGT0 + N_TGT1) * 4);
    int* head1 = head0 + N_TGT0;
    int* next0 = (int*)take((size_t)E0 * 4);
    int* next1 = (int*)take((size_t)E1 * 4);

    hipMemsetAsync(head0, 0xFF, (size_t)(N_TGT0 + N_TGT1) * sizeof(int), stream);

    build_kernel<<<(NWK + 255) / 256, 256, 0, stream>>>(
        src0, dst0, src1, dst1, head0, next0, head1, next1, Wl1, Wr1, BT);

    agg0_ll<<<N_TGT0 / 4, 256, 0, stream>>>(x, head0, next0, src0, A);

    gemm1_tile<<<640, 256, 0, stream>>>(A, BT, b1, h);

    out_fused<<<N_TGT1, 64, 0, stream>>>(h, head1, next1, src1, Wl2, Wr2, b2, out);
}